// Round 7
// baseline (154.736 us; speedup 1.0000x reference)
//
#include <hip/hip_runtime.h>

#define FD     41024   // FEATURES_DIM = 64*(64*10+1)
#define KBASE  641     // 64*10+1
#define WIN    320     // hot window: offsets (piece)*64+sq span 0..319
#define SLDS   324     // LDS row stride (16B-aligned, covers WIN + 3 shift)
#define ROWG   16      // rows per block
#define NB_MAX 1024

// workspace layout (int32 units)
#define WS_OFF0  0                        // [1024][64] opp-piece offsets (h[0:256] via W_my)
#define WS_OFF1  (NB_MAX*64)              // [1024][64] my-piece offsets  (h[256:512] via W_opp)
#define WS_N0    (2*NB_MAX*64)            // [1024]
#define WS_N1    (WS_N0 + NB_MAX)
#define WS_KMY   (WS_N1 + NB_MAX)         // my king square
#define WS_KOPP  (WS_KMY + NB_MAX)        // opp king square
#define WS_H     (WS_KOPP + NB_MAX)       // float h[1024][512] (post bias+relu)

// ---------------------------------------------------------------------------
// Node 1: classify squares into offset lists + kings.
// ---------------------------------------------------------------------------
__global__ __launch_bounds__(64) void classify(
    const int* __restrict__ boards, int* __restrict__ ws)
{
    __shared__ int s_off0[64], s_off1[64];
    __shared__ int s_cnt[2], s_k[2];
    const int b = blockIdx.x;
    const int t = threadIdx.x;

    s_off0[t] = 0; s_off1[t] = 0;
    if (t < 2) s_cnt[t] = 0;
    __syncthreads();

    const int d = boards[b * 64 + t];
    if (d == 0)       s_k[0] = t;
    else if (d == 12) s_k[1] = t;
    else if (d >= 1 && d <= 5) { int p = atomicAdd(&s_cnt[1], 1); s_off1[p] = (d - 1) * 64 + t; }
    else if (d >= 7 && d <= 11){ int p = atomicAdd(&s_cnt[0], 1); s_off0[p] = (11 - d) * 64 + t; }
    __syncthreads();

    ws[WS_OFF0 + b * 64 + t] = s_off0[t];
    ws[WS_OFF1 + b * 64 + t] = s_off1[t];
    if (t == 0) {
        ws[WS_N0   + b] = s_cnt[0];
        ws[WS_N1   + b] = s_cnt[1];
        ws[WS_KMY  + b] = s_k[0];
        ws[WS_KOPP + b] = s_k[1];
    }
}

// ---------------------------------------------------------------------------
// Node 2: bucketed first layer + fused bias/relu.
// Block = (m, king, 16-row group). LDS ~29 KB -> 5 blocks/CU; 2048 blocks.
// Staging global loads are issued BEFORE the bucket scan so L2/L3 latency
// overlaps the scan; ds_writes land after the scan's barrier.
// ---------------------------------------------------------------------------
__global__ __launch_bounds__(256) void gather_bucketed(
    const float* __restrict__ W_my, const float* __restrict__ W_opp,
    const float* __restrict__ b_my, const float* __restrict__ b_opp,
    const int* __restrict__ ws, float* __restrict__ h, int nb)
{
    __shared__ float win[ROWG * SLDS];   // 20.7 KB
    __shared__ int   s_list[NB_MAX];     // 4 KB
    __shared__ int   goffs[16 * 64];     // 4 KB
    __shared__ int   s_cnt;

    const int blk = blockIdx.x;          // 0..2047
    const int rg  = blk & 15;            // 16-row group
    const int k   = (blk >> 4) & 63;     // king square
    const int m   = blk >> 10;           // 0: W_my/opp-king, 1: W_opp/my-king
    const int t   = threadIdx.x;

    // ---- issue staging loads first (addresses independent of bucket list)
    const int shift = (k * KBASE) & 3;
    const int cs    = k * KBASE - shift;
    const float* __restrict__ W = m ? W_opp : W_my;
    const size_t gbase = (size_t)(rg * ROWG) * FD + (size_t)cs;
    float4 v[6];
    int    vidx[6];
    #pragma unroll
    for (int u = 0; u < 6; u++) {        // 16 rows * 81 float4 = 1296
        int idx = u * 256 + t;
        vidx[u] = idx;
        if (idx > 1295) idx = 1295;      // clamped duplicate load, always in-bounds
        const int r  = idx / 81;
        const int c4 = idx - r * 81;
        v[u] = *(const float4*)(W + gbase + (size_t)r * FD + c4 * 4);
    }

    // ---- bucket scan (overlaps the in-flight loads)
    if (t == 0) s_cnt = 0;
    __syncthreads();
    const int* __restrict__ karr = ws + (m ? WS_KMY : WS_KOPP);
    for (int i = t; i < nb; i += 256)
        if (karr[i] == k) { int p = atomicAdd(&s_cnt, 1); s_list[p] = i; }
    __syncthreads();

    const int n_b = s_cnt;
    if (n_b == 0) return;

    #pragma unroll
    for (int u = 0; u < 6; u++) {
        const int idx = vidx[u];
        if (idx < 1296) {
            const int r  = idx / 81;
            const int c4 = idx - r * 81;
            *(float4*)(&win[r * SLDS + c4 * 4]) = v[u];
        }
    }
    __syncthreads();

    const int* __restrict__ offarr = ws + (m ? WS_OFF1 : WS_OFF0);
    const int* __restrict__ narr   = ws + (m ? WS_N1   : WS_N0);
    const int r    = t & 15;
    const int slot = t >> 4;             // 16 boards in parallel
    const float bias = (m ? b_opp : b_my)[rg * ROWG + r];
    const int hcol = m * 256 + rg * ROWG + r;
    const float* __restrict__ wrow = &win[r * SLDS + shift];

    for (int g = 0; g < n_b; g += 16) {
        // cooperative stage of up to 16 boards' offset lists (int4 each)
        {
            const int bi = g + (t >> 4);         // 256 threads = 16 boards x 16 int4
            if (bi < n_b) {
                const int4 o4 = *(const int4*)(offarr + s_list[bi] * 64 + (t & 15) * 4);
                *(int4*)(&goffs[(t >> 4) * 64 + (t & 15) * 4]) = o4;
            }
        }
        __syncthreads();

        const int bi = g + slot;
        if (bi < n_b) {
            const int board = s_list[bi];
            const int nf = narr[board];
            const int* __restrict__ lo = &goffs[slot * 64];
            float acc0 = 0.0f, acc1 = 0.0f;
            int i = 0;
            for (; i + 4 <= nf; i += 4) {
                acc0 += wrow[lo[i]]     + wrow[lo[i + 1]];
                acc1 += wrow[lo[i + 2]] + wrow[lo[i + 3]];
            }
            for (; i < nf; i++) acc0 += wrow[lo[i]];
            h[(size_t)board * 512 + hcol] = fmaxf(acc0 + acc1 + bias, 0.0f);
        }
        __syncthreads();
    }
}

// ---------------------------------------------------------------------------
// Node 3: MLP tail (h already bias+relu'd). One block per board.
// ---------------------------------------------------------------------------
__global__ __launch_bounds__(256) void mlp_tail(
    const float* __restrict__ h,
    const float* __restrict__ W1, const float* __restrict__ b1,
    const float* __restrict__ W2, const float* __restrict__ b2,
    const float* __restrict__ W3, const float* __restrict__ b3,
    float* __restrict__ out)
{
    __shared__ float s_h[512];
    __shared__ float s_h1[32];
    const int b = blockIdx.x;
    const int t = threadIdx.x;

    s_h[t]       = h[(size_t)b * 512 + t];
    s_h[256 + t] = h[(size_t)b * 512 + 256 + t];
    __syncthreads();

    {
        const int o = t >> 3, l = t & 7;
        const float* __restrict__ w = W1 + o * 512;
        float p = 0.0f;
        for (int kk = l; kk < 512; kk += 8) p += s_h[kk] * w[kk];
        p += __shfl_down(p, 4, 8);
        p += __shfl_down(p, 2, 8);
        p += __shfl_down(p, 1, 8);
        if (l == 0) s_h1[o] = fmaxf(p + b1[o], 0.0f);
    }
    __syncthreads();

    if (t < 32) {
        const float* __restrict__ w = W2 + t * 32;
        float acc = b2[t];
        for (int kk = 0; kk < 32; kk++) acc += s_h1[kk] * w[kk];
        float h2 = fmaxf(acc, 0.0f);
        float p = h2 * W3[t];
        p += __shfl_down(p, 16, 32);
        p += __shfl_down(p,  8, 32);
        p += __shfl_down(p,  4, 32);
        p += __shfl_down(p,  2, 32);
        p += __shfl_down(p,  1, 32);
        if (t == 0) out[b] = p + b3[0];
    }
}

// ---------------------------------------------------------------------------
// Fallback (R1 kernel): direct strided gather — used only if d_ws too small.
// ---------------------------------------------------------------------------
__global__ __launch_bounds__(256) void nnue_fwd(
    const int*   __restrict__ boards,
    const float* __restrict__ W_my,  const float* __restrict__ b_my,
    const float* __restrict__ W_opp, const float* __restrict__ b_opp,
    const float* __restrict__ W1,    const float* __restrict__ b1,
    const float* __restrict__ W2,    const float* __restrict__ b2,
    const float* __restrict__ W3,    const float* __restrict__ b3,
    float* __restrict__ out)
{
    __shared__ int   s_off0[64], s_off1[64];
    __shared__ int   s_cnt[2], s_kings[2];
    __shared__ float s_h[512];
    __shared__ float s_h1[32];

    const int b = blockIdx.x;
    const int t = threadIdx.x;

    if (t < 2) s_cnt[t] = 0;
    __syncthreads();

    if (t < 64) {
        int d = boards[b * 64 + t];
        if (d == 0)       s_kings[0] = t;
        else if (d == 12) s_kings[1] = t;
        else if (d >= 1 && d <= 5) { int p = atomicAdd(&s_cnt[1], 1); s_off1[p] = (d - 1) * 64 + t; }
        else if (d >= 7)           { int p = atomicAdd(&s_cnt[0], 1); s_off0[p] = (11 - d) * 64 + t; }
    }
    __syncthreads();

    const int n0 = s_cnt[0], n1 = s_cnt[1];
    const int base0 = s_kings[1] * KBASE;
    const int base1 = s_kings[0] * KBASE;

    {
        const float* __restrict__ w = W_my + (size_t)t * FD + base0;
        float acc = b_my[t];
        for (int i = 0; i < n0; i++) acc += w[s_off0[i]];
        s_h[t] = fmaxf(acc, 0.0f);
    }
    {
        const float* __restrict__ w = W_opp + (size_t)t * FD + base1;
        float acc = b_opp[t];
        for (int i = 0; i < n1; i++) acc += w[s_off1[i]];
        s_h[256 + t] = fmaxf(acc, 0.0f);
    }
    __syncthreads();

    {
        const int o = t >> 3, l = t & 7;
        const float* __restrict__ w = W1 + o * 512;
        float p = 0.0f;
        for (int kk = l; kk < 512; kk += 8) p += s_h[kk] * w[kk];
        p += __shfl_down(p, 4, 8);
        p += __shfl_down(p, 2, 8);
        p += __shfl_down(p, 1, 8);
        if (l == 0) s_h1[o] = fmaxf(p + b1[o], 0.0f);
    }
    __syncthreads();

    if (t < 32) {
        const float* __restrict__ w = W2 + t * 32;
        float acc = b2[t];
        for (int kk = 0; kk < 32; kk++) acc += s_h1[kk] * w[kk];
        float h2 = fmaxf(acc, 0.0f);
        float p = h2 * W3[t];
        p += __shfl_down(p, 16, 32);
        p += __shfl_down(p,  8, 32);
        p += __shfl_down(p,  4, 32);
        p += __shfl_down(p,  2, 32);
        p += __shfl_down(p,  1, 32);
        if (t == 0) out[b] = p + b3[0];
    }
}

extern "C" void kernel_launch(void* const* d_in, const int* in_sizes, int n_in,
                              void* d_out, int out_size, void* d_ws, size_t ws_size,
                              hipStream_t stream) {
    const int*   boards = (const int*)  d_in[0];
    const float* W_my   = (const float*)d_in[1];
    const float* b_my   = (const float*)d_in[2];
    const float* W_opp  = (const float*)d_in[3];
    const float* b_opp  = (const float*)d_in[4];
    const float* W1     = (const float*)d_in[5];
    const float* b1     = (const float*)d_in[6];
    const float* W2     = (const float*)d_in[7];
    const float* b2     = (const float*)d_in[8];
    const float* W3     = (const float*)d_in[9];
    const float* b3     = (const float*)d_in[10];
    float* out = (float*)d_out;

    const int nb = in_sizes[0] / 64;
    const size_t ws_needed = (size_t)(WS_H + (size_t)NB_MAX * 512) * sizeof(int);

    if (nb <= NB_MAX && ws_size >= ws_needed) {
        int*   wsi = (int*)d_ws;
        float* h   = (float*)d_ws + WS_H;
        classify<<<nb, 64, 0, stream>>>(boards, wsi);
        gather_bucketed<<<2048, 256, 0, stream>>>(W_my, W_opp, b_my, b_opp, wsi, h, nb);
        mlp_tail<<<nb, 256, 0, stream>>>(h, W1, b1, W2, b2, W3, b3, out);
    } else {
        nnue_fwd<<<nb, 256, 0, stream>>>(boards, W_my, b_my, W_opp, b_opp,
                                         W1, b1, W2, b2, W3, b3, out);
    }
}

// Round 9
// 144.712 us; speedup vs baseline: 1.0693x; 1.0693x over previous
//
#include <hip/hip_runtime.h>

#define FD     41024   // FEATURES_DIM = 64*(64*10+1)
#define KBASE  641     // 64*10+1
#define WIN    320     // hot window: offsets (piece)*64+sq span 0..319
#define SLDS   324     // LDS row stride (16B-aligned, covers WIN + 3 shift)
#define NB_MAX 1024

// workspace layout (int32 units)
#define WS_OFF0  0                        // [1024][64] opp-piece offsets (h[0:256] via W_my)
#define WS_OFF1  (NB_MAX*64)              // [1024][64] my-piece offsets  (h[256:512] via W_opp)
#define WS_N0    (2*NB_MAX*64)            // [1024]
#define WS_N1    (WS_N0 + NB_MAX)
#define WS_KMY   (WS_N1 + NB_MAX)         // my king square
#define WS_KOPP  (WS_KMY + NB_MAX)        // opp king square
#define WS_H     (WS_KOPP + NB_MAX)       // float h[1024][512] (post bias+relu)

// ---------------------------------------------------------------------------
// Node 1: classify squares into offset lists + kings.
// ---------------------------------------------------------------------------
__global__ __launch_bounds__(64) void classify(
    const int* __restrict__ boards, int* __restrict__ ws)
{
    __shared__ int s_off0[64], s_off1[64];
    __shared__ int s_cnt[2], s_k[2];
    const int b = blockIdx.x;
    const int t = threadIdx.x;

    s_off0[t] = 0; s_off1[t] = 0;
    if (t < 2) s_cnt[t] = 0;
    __syncthreads();

    const int d = boards[b * 64 + t];
    if (d == 0)       s_k[0] = t;
    else if (d == 12) s_k[1] = t;
    else if (d >= 1 && d <= 5) { int p = atomicAdd(&s_cnt[1], 1); s_off1[p] = (d - 1) * 64 + t; }
    else if (d >= 7 && d <= 11){ int p = atomicAdd(&s_cnt[0], 1); s_off0[p] = (11 - d) * 64 + t; }
    __syncthreads();

    ws[WS_OFF0 + b * 64 + t] = s_off0[t];
    ws[WS_OFF1 + b * 64 + t] = s_off1[t];
    if (t == 0) {
        ws[WS_N0   + b] = s_cnt[0];
        ws[WS_N1   + b] = s_cnt[1];
        ws[WS_KMY  + b] = s_k[0];
        ws[WS_KOPP + b] = s_k[1];
    }
}

// ---------------------------------------------------------------------------
// Node 2: bucketed first layer + fused bias/relu. Block = (m, king, rowgroup).
// Window staged ROW-MAJOR in LDS with stride 324: global_load_dwordx4 +
// ds_write_b128 staging. Compute reads win[r*324 + off+shift].
// ---------------------------------------------------------------------------
__global__ __launch_bounds__(256) void gather_bucketed(
    const float* __restrict__ W_my, const float* __restrict__ W_opp,
    const float* __restrict__ b_my, const float* __restrict__ b_opp,
    const int* __restrict__ ws, float* __restrict__ h, int nb)
{
    __shared__ float win[32 * SLDS];     // 41.5 KB
    __shared__ int   s_list[NB_MAX];
    __shared__ int   goffs[8 * 64];
    __shared__ int   s_cnt;

    const int blk = blockIdx.x;          // 0..1023
    const int rg  = blk & 7;             // rowgroup (32 rows)
    const int k   = (blk >> 3) & 63;     // king square
    const int m   = blk >> 9;            // 0: W_my/opp-king, 1: W_opp/my-king
    const int t   = threadIdx.x;

    if (t == 0) s_cnt = 0;
    __syncthreads();

    const int* __restrict__ karr = ws + (m ? WS_KMY : WS_KOPP);
    for (int i = t; i < nb; i += 256)
        if (karr[i] == k) { int p = atomicAdd(&s_cnt, 1); s_list[p] = i; }
    __syncthreads();

    const int n_b = s_cnt;
    if (n_b == 0) return;

    // stage rows [rg*32, rg*32+32) x cols [cs, cs+324), cs 16B-aligned
    const int shift = (k * KBASE) & 3;
    const int cs    = k * KBASE - shift;
    const float* __restrict__ W = m ? W_opp : W_my;
    const size_t gbase = (size_t)(rg * 32) * FD + (size_t)cs;
    #pragma unroll
    for (int u = 0; u < 11; u++) {       // 32 rows * 81 float4 = 2592
        const int idx = u * 256 + t;
        if (idx < 2592) {
            const int r  = idx / 81;
            const int c4 = idx - r * 81;
            const float4 v = *(const float4*)(W + gbase + (size_t)r * FD + c4 * 4);
            *(float4*)(&win[r * SLDS + c4 * 4]) = v;
        }
    }
    __syncthreads();

    const int* __restrict__ offarr = ws + (m ? WS_OFF1 : WS_OFF0);
    const int* __restrict__ narr   = ws + (m ? WS_N1   : WS_N0);
    const int r    = t & 31;
    const int slot = t >> 5;             // 8 boards in parallel
    const float bias = (m ? b_opp : b_my)[rg * 32 + r];
    const int hcol = m * 256 + rg * 32 + r;
    const float* __restrict__ wrow = &win[r * SLDS + shift];

    for (int g = 0; g < n_b; g += 8) {
        // cooperative stage of up to 8 boards' offset lists (int4)
        {
            const int j  = t;            // 128 int4 = 512 ints
            if (j < 128) {
                const int bi = g + (j >> 4);
                if (bi < n_b) {
                    const int4 v = *(const int4*)(offarr + s_list[bi] * 64 + (j & 15) * 4);
                    *(int4*)(&goffs[j * 4]) = v;
                }
            }
        }
        __syncthreads();

        const int bi = g + slot;
        if (bi < n_b) {
            const int board = s_list[bi];
            const int nf = narr[board];
            const int* __restrict__ lo = &goffs[slot * 64];
            float acc0 = 0.0f, acc1 = 0.0f;
            int i = 0;
            for (; i + 4 <= nf; i += 4) {
                acc0 += wrow[lo[i]]     + wrow[lo[i + 1]];
                acc1 += wrow[lo[i + 2]] + wrow[lo[i + 3]];
            }
            for (; i < nf; i++) acc0 += wrow[lo[i]];
            h[(size_t)board * 512 + hcol] = fmaxf(acc0 + acc1 + bias, 0.0f);
        }
        __syncthreads();
    }
}

// ---------------------------------------------------------------------------
// Node 3: MLP tail (h already bias+relu'd). One block per board.
// ---------------------------------------------------------------------------
__global__ __launch_bounds__(256) void mlp_tail(
    const float* __restrict__ h,
    const float* __restrict__ W1, const float* __restrict__ b1,
    const float* __restrict__ W2, const float* __restrict__ b2,
    const float* __restrict__ W3, const float* __restrict__ b3,
    float* __restrict__ out)
{
    __shared__ float s_h[512];
    __shared__ float s_h1[32];
    const int b = blockIdx.x;
    const int t = threadIdx.x;

    s_h[t]       = h[(size_t)b * 512 + t];
    s_h[256 + t] = h[(size_t)b * 512 + 256 + t];
    __syncthreads();

    {
        const int o = t >> 3, l = t & 7;
        const float* __restrict__ w = W1 + o * 512;
        float p = 0.0f;
        for (int kk = l; kk < 512; kk += 8) p += s_h[kk] * w[kk];
        p += __shfl_down(p, 4, 8);
        p += __shfl_down(p, 2, 8);
        p += __shfl_down(p, 1, 8);
        if (l == 0) s_h1[o] = fmaxf(p + b1[o], 0.0f);
    }
    __syncthreads();

    if (t < 32) {
        const float* __restrict__ w = W2 + t * 32;
        float acc = b2[t];
        for (int kk = 0; kk < 32; kk++) acc += s_h1[kk] * w[kk];
        float h2 = fmaxf(acc, 0.0f);
        float p = h2 * W3[t];
        p += __shfl_down(p, 16, 32);
        p += __shfl_down(p,  8, 32);
        p += __shfl_down(p,  4, 32);
        p += __shfl_down(p,  2, 32);
        p += __shfl_down(p,  1, 32);
        if (t == 0) out[b] = p + b3[0];
    }
}

// ---------------------------------------------------------------------------
// Fallback (R1 kernel): direct strided gather — used only if d_ws too small.
// ---------------------------------------------------------------------------
__global__ __launch_bounds__(256) void nnue_fwd(
    const int*   __restrict__ boards,
    const float* __restrict__ W_my,  const float* __restrict__ b_my,
    const float* __restrict__ W_opp, const float* __restrict__ b_opp,
    const float* __restrict__ W1,    const float* __restrict__ b1,
    const float* __restrict__ W2,    const float* __restrict__ b2,
    const float* __restrict__ W3,    const float* __restrict__ b3,
    float* __restrict__ out)
{
    __shared__ int   s_off0[64], s_off1[64];
    __shared__ int   s_cnt[2], s_kings[2];
    __shared__ float s_h[512];
    __shared__ float s_h1[32];

    const int b = blockIdx.x;
    const int t = threadIdx.x;

    if (t < 2) s_cnt[t] = 0;
    __syncthreads();

    if (t < 64) {
        int d = boards[b * 64 + t];
        if (d == 0)       s_kings[0] = t;
        else if (d == 12) s_kings[1] = t;
        else if (d >= 1 && d <= 5) { int p = atomicAdd(&s_cnt[1], 1); s_off1[p] = (d - 1) * 64 + t; }
        else if (d >= 7)           { int p = atomicAdd(&s_cnt[0], 1); s_off0[p] = (11 - d) * 64 + t; }
    }
    __syncthreads();

    const int n0 = s_cnt[0], n1 = s_cnt[1];
    const int base0 = s_kings[1] * KBASE;
    const int base1 = s_kings[0] * KBASE;

    {
        const float* __restrict__ w = W_my + (size_t)t * FD + base0;
        float acc = b_my[t];
        for (int i = 0; i < n0; i++) acc += w[s_off0[i]];
        s_h[t] = fmaxf(acc, 0.0f);
    }
    {
        const float* __restrict__ w = W_opp + (size_t)t * FD + base1;
        float acc = b_opp[t];
        for (int i = 0; i < n1; i++) acc += w[s_off1[i]];
        s_h[256 + t] = fmaxf(acc, 0.0f);
    }
    __syncthreads();

    {
        const int o = t >> 3, l = t & 7;
        const float* __restrict__ w = W1 + o * 512;
        float p = 0.0f;
        for (int kk = l; kk < 512; kk += 8) p += s_h[kk] * w[kk];
        p += __shfl_down(p, 4, 8);
        p += __shfl_down(p, 2, 8);
        p += __shfl_down(p, 1, 8);
        if (l == 0) s_h1[o] = fmaxf(p + b1[o], 0.0f);
    }
    __syncthreads();

    if (t < 32) {
        const float* __restrict__ w = W2 + t * 32;
        float acc = b2[t];
        for (int kk = 0; kk < 32; kk++) acc += s_h1[kk] * w[kk];
        float h2 = fmaxf(acc, 0.0f);
        float p = h2 * W3[t];
        p += __shfl_down(p, 16, 32);
        p += __shfl_down(p,  8, 32);
        p += __shfl_down(p,  4, 32);
        p += __shfl_down(p,  2, 32);
        p += __shfl_down(p,  1, 32);
        if (t == 0) out[b] = p + b3[0];
    }
}

extern "C" void kernel_launch(void* const* d_in, const int* in_sizes, int n_in,
                              void* d_out, int out_size, void* d_ws, size_t ws_size,
                              hipStream_t stream) {
    const int*   boards = (const int*)  d_in[0];
    const float* W_my   = (const float*)d_in[1];
    const float* b_my   = (const float*)d_in[2];
    const float* W_opp  = (const float*)d_in[3];
    const float* b_opp  = (const float*)d_in[4];
    const float* W1     = (const float*)d_in[5];
    const float* b1     = (const float*)d_in[6];
    const float* W2     = (const float*)d_in[7];
    const float* b2     = (const float*)d_in[8];
    const float* W3     = (const float*)d_in[9];
    const float* b3     = (const float*)d_in[10];
    float* out = (float*)d_out;

    const int nb = in_sizes[0] / 64;
    const size_t ws_needed = (size_t)(WS_H + (size_t)NB_MAX * 512) * sizeof(int);

    if (nb <= NB_MAX && ws_size >= ws_needed) {
        int*   wsi = (int*)d_ws;
        float* h   = (float*)d_ws + WS_H;
        classify<<<nb, 64, 0, stream>>>(boards, wsi);
        gather_bucketed<<<1024, 256, 0, stream>>>(W_my, W_opp, b_my, b_opp, wsi, h, nb);
        mlp_tail<<<nb, 256, 0, stream>>>(h, W1, b1, W2, b2, W3, b3, out);
    } else {
        nnue_fwd<<<nb, 256, 0, stream>>>(boards, W_my, b_my, W_opp, b_opp,
                                         W1, b1, W2, b2, W3, b3, out);
    }
}